// Round 4
// baseline (1782.293 us; speedup 1.0000x reference)
//
#include <hip/hip_runtime.h>
#include <hip/hip_bf16.h>
#include <math.h>

#define NN 100000
#define NE 3200000
#define NF 512
#define NTILE 6250   // NN/16 exactly
#define NB 782       // ceil(NN/128) dst-buckets of 128 nodes

typedef __attribute__((ext_vector_type(8))) short short8;
typedef __attribute__((ext_vector_type(4))) float f32x4;

__device__ inline unsigned bf16_rne(float f) {
    unsigned u = __builtin_bit_cast(unsigned, f);
    return (u + 0x7FFFu + ((u >> 16) & 1u)) >> 16;
}
__device__ inline float bf16_back(unsigned h) {
    return __builtin_bit_cast(float, h << 16);
}

// ---------------- init: bucket_cnt=0, pooled=0 ----------------
__global__ void k_init(int* __restrict__ bucket_cnt, float* __restrict__ pooled) {
    int i = threadIdx.x;
    if (i < NB) bucket_cnt[i] = 0;
    if (i < 16) pooled[i] = 0.0f;
}

// ---------------- bucket histogram via LDS pre-aggregation ----------------
__global__ __launch_bounds__(256) void k_bcount(const int* __restrict__ dst,
                                                int* __restrict__ bucket_cnt) {
    __shared__ int lcnt[NB];
    for (int i = threadIdx.x; i < NB; i += 256) lcnt[i] = 0;
    __syncthreads();
    for (int e = blockIdx.x * 256 + threadIdx.x; e < NE; e += gridDim.x * 256)
        atomicAdd(&lcnt[dst[e] >> 7], 1);
    __syncthreads();
    for (int i = threadIdx.x; i < NB; i += 256) {
        int v = lcnt[i];
        if (v) atomicAdd(&bucket_cnt[i], v);
    }
}

// ---------------- exclusive scan of bucket_cnt -> bucket_start, bcursor --------
__global__ __launch_bounds__(1024) void k_prep(const int* __restrict__ bucket_cnt,
                                               int* __restrict__ bucket_start,
                                               int* __restrict__ bcursor) {
    __shared__ int tmp[2][1024];
    int tid = threadIdx.x;
    int v = (tid < NB) ? bucket_cnt[tid] : 0;
    int pp = 0;
    tmp[0][tid] = v;
    __syncthreads();
    for (int off = 1; off < 1024; off <<= 1) {
        int t = tmp[pp][tid];
        if (tid >= off) t += tmp[pp][tid - off];
        tmp[1 - pp][tid] = t;
        __syncthreads();
        pp = 1 - pp;
    }
    if (tid < NB) {
        int excl = tmp[pp][tid] - v;
        bucket_start[tid] = excl;
        bcursor[tid] = excl;
    }
    if (tid == 0) bucket_start[NB] = NE;
}

// ---------------- placement: append packed (dlow<<17 | src) per bucket --------
__global__ __launch_bounds__(256) void k_place(const int* __restrict__ src,
                                               const int* __restrict__ dst,
                                               int* __restrict__ bcursor,
                                               unsigned* __restrict__ packed) {
    int e = blockIdx.x * 256 + threadIdx.x;
    if (e >= NE) return;
    int d = dst[e];
    int b = d >> 7;
    int pos = atomicAdd(&bcursor[b], 1);
    packed[pos] = ((unsigned)(d & 127) << 17) | (unsigned)src[e];
}

// ---------------- per-bucket degree -> dinv ----------------
__global__ __launch_bounds__(256) void k_dinv(const unsigned* __restrict__ packed,
                                              const int* __restrict__ bucket_start,
                                              float* __restrict__ dinv) {
    __shared__ int lcnt[128];
    if (threadIdx.x < 128) lcnt[threadIdx.x] = 0;
    __syncthreads();
    const int beg = bucket_start[blockIdx.x], end = bucket_start[blockIdx.x + 1];
    for (int i = beg + threadIdx.x; i < end; i += 256)
        atomicAdd(&lcnt[packed[i] >> 17], 1);
    __syncthreads();
    if (threadIdx.x < 128) {
        int n = blockIdx.x * 128 + threadIdx.x;
        if (n < NN) dinv[n] = rsqrtf((float)lcnt[threadIdx.x] + 1.0f);
    }
}

// ---------------- GEMM1 via MFMA 16x16x32 bf16, split hi/lo ----------------
// Writes hs[n][c] = dinv[n] * (x@W1)[n][c]
__global__ __launch_bounds__(256) void k_gemm1(
    const float* __restrict__ x, const float* __restrict__ W1,
    const float* __restrict__ dinv, float* __restrict__ hs) {
    __shared__ short8 Bh[1024];  // idx = (kk*4+q)*16 + c
    __shared__ short8 Bl[1024];

    const int t = threadIdx.x;
    {   // stage W: thread (c,q,kk0) handles kk = kk0*4+i
        const int c = t & 15, q = (t >> 4) & 3, kk0 = t >> 6;
        for (int i = 0; i < 4; ++i) {
            const int kk = kk0 * 4 + i;
            short8 hi, lo;
#pragma unroll
            for (int j = 0; j < 8; ++j) {
                float w = W1[(kk * 32 + q * 8 + j) * 16 + c];
                unsigned h = bf16_rne(w);
                float back = bf16_back(h);
                unsigned l = bf16_rne(w - back);
                hi[j] = (short)h;
                lo[j] = (short)l;
            }
            Bh[(kk * 4 + q) * 16 + c] = hi;
            Bl[(kk * 4 + q) * 16 + c] = lo;
        }
    }
    __syncthreads();

    const int lane = t & 63;
    const int wave = blockIdx.x * 4 + (t >> 6);
    if (wave >= NTILE) return;
    const int nb = wave * 16;
    const int m = lane & 15;  // A row within tile AND B/C col (channel)
    const int q = lane >> 4;

    const float4* xrow = (const float4*)(x + (size_t)(nb + m) * NF + q * 8);
    float4 xr[32];
#pragma unroll
    for (int kk = 0; kk < 16; ++kk) {
        xr[2 * kk] = xrow[kk * 8];
        xr[2 * kk + 1] = xrow[kk * 8 + 1];
    }

    f32x4 acc = {0.f, 0.f, 0.f, 0.f};
#pragma unroll
    for (int kk = 0; kk < 16; ++kk) {
        float f[8] = {xr[2 * kk].x,     xr[2 * kk].y,     xr[2 * kk].z,
                      xr[2 * kk].w,     xr[2 * kk + 1].x, xr[2 * kk + 1].y,
                      xr[2 * kk + 1].z, xr[2 * kk + 1].w};
        short8 ah, al;
#pragma unroll
        for (int j = 0; j < 8; ++j) {
            unsigned h = bf16_rne(f[j]);
            ah[j] = (short)h;
            al[j] = (short)bf16_rne(f[j] - bf16_back(h));
        }
        short8 bh = Bh[(kk * 4 + q) * 16 + m];
        short8 bl = Bl[(kk * 4 + q) * 16 + m];
        acc = __builtin_amdgcn_mfma_f32_16x16x32_bf16(ah, bh, acc, 0, 0, 0);
        acc = __builtin_amdgcn_mfma_f32_16x16x32_bf16(ah, bl, acc, 0, 0, 0);
        acc = __builtin_amdgcn_mfma_f32_16x16x32_bf16(al, bh, acc, 0, 0, 0);
    }

    // C/D: col=lane&15, row=q*4+reg
#pragma unroll
    for (int r = 0; r < 4; ++r) {
        const int n = nb + q * 4 + r;
        hs[n * 16 + m] = dinv[n] * acc[r];
    }
}

// ---------------- agg1: layer-1 aggregate + relu + @W2 fused ----------------
// out hs2[n] = dinv[n] * ( relu( dinv[n]*(sum_in hs[s] + hs[n]) + b1 ) @ W2 )
__global__ __launch_bounds__(256) void k_agg1(
    const float* __restrict__ hs, const float* __restrict__ dinv,
    const int* __restrict__ bucket_start, const unsigned* __restrict__ packed,
    const float* __restrict__ W2, const float* __restrict__ b1,
    float* __restrict__ hs2) {
    __shared__ float acc[128 * 16];  // 8 KB
    const int tid = threadIdx.x;
    const int c = tid & 15;
    const int g = tid >> 4;  // 16 edge-groups
#pragma unroll
    for (int i = 0; i < 8; ++i) acc[tid + 256 * i] = 0.0f;

    float w2c[16];
#pragma unroll
    for (int k = 0; k < 16; ++k) w2c[k] = W2[k * 16 + c];
    const float b1c = b1[c];
    __syncthreads();

    const int beg = bucket_start[blockIdx.x], end = bucket_start[blockIdx.x + 1];
    int i = beg + g;
    for (; i + 16 < end; i += 32) {  // 2 edges in flight per group
        unsigned p0 = packed[i], p1 = packed[i + 16];
        float v0 = hs[(p0 & 0x1FFFF) * 16 + c];
        float v1 = hs[(p1 & 0x1FFFF) * 16 + c];
        atomicAdd(&acc[(p0 >> 17) * 16 + c], v0);
        atomicAdd(&acc[(p1 >> 17) * 16 + c], v1);
    }
    if (i < end) {
        unsigned p0 = packed[i];
        atomicAdd(&acc[(p0 >> 17) * 16 + c], hs[(p0 & 0x1FFFF) * 16 + c]);
    }
    __syncthreads();

    const int n0 = blockIdx.x * 128;
#pragma unroll
    for (int r = 0; r < 8; ++r) {
        const int nl = g + 16 * r;
        const int n = n0 + nl;
        if (n < NN) {
            float di = dinv[n];
            float a1 = di * (acc[nl * 16 + c] + hs[n * 16 + c]);
            float h2 = fmaxf(a1 + b1c, 0.0f);
            acc[nl * 16 + c] = h2;  // same 16-lane group reads back below
            float dot = 0.0f;
#pragma unroll
            for (int k = 0; k < 16; ++k) dot += acc[nl * 16 + k] * w2c[k];
            hs2[n * 16 + c] = di * dot;
        }
    }
}

// ---------------- agg2: layer-2 aggregate + mean-pool partial sums ------------
__global__ __launch_bounds__(256) void k_agg2(
    const float* __restrict__ hs2, const float* __restrict__ dinv,
    const int* __restrict__ bucket_start, const unsigned* __restrict__ packed,
    float* __restrict__ pooled) {
    __shared__ float acc[128 * 16];  // 8 KB
    __shared__ float red[16 * 16];
    const int tid = threadIdx.x;
    const int c = tid & 15;
    const int g = tid >> 4;
#pragma unroll
    for (int i = 0; i < 8; ++i) acc[tid + 256 * i] = 0.0f;
    __syncthreads();

    const int beg = bucket_start[blockIdx.x], end = bucket_start[blockIdx.x + 1];
    int i = beg + g;
    for (; i + 16 < end; i += 32) {
        unsigned p0 = packed[i], p1 = packed[i + 16];
        float v0 = hs2[(p0 & 0x1FFFF) * 16 + c];
        float v1 = hs2[(p1 & 0x1FFFF) * 16 + c];
        atomicAdd(&acc[(p0 >> 17) * 16 + c], v0);
        atomicAdd(&acc[(p1 >> 17) * 16 + c], v1);
    }
    if (i < end) {
        unsigned p0 = packed[i];
        atomicAdd(&acc[(p0 >> 17) * 16 + c], hs2[(p0 & 0x1FFFF) * 16 + c]);
    }
    __syncthreads();

    const int n0 = blockIdx.x * 128;
    float psum = 0.0f;
#pragma unroll
    for (int r = 0; r < 8; ++r) {
        const int nl = g + 16 * r;
        const int n = n0 + nl;
        if (n < NN) {
            float di = dinv[n];
            psum += di * (acc[nl * 16 + c] + hs2[n * 16 + c]);
        }
    }
    red[g * 16 + c] = psum;
    __syncthreads();
    if (tid < 16) {
        float tot = 0.0f;
#pragma unroll
        for (int k = 0; k < 16; ++k) tot += red[k * 16 + tid];
        atomicAdd(&pooled[tid], tot);
    }
}

// ---------------- softmax over 16 pooled means + b2 ----------------
__global__ void k_softmax(const float* __restrict__ pooled,
                          const float* __restrict__ b2, float* __restrict__ out) {
    __shared__ float vals[16];
    int c = threadIdx.x;
    if (c < 16) vals[c] = pooled[c] * (1.0f / NN) + b2[c];
    __syncthreads();
    if (c < 16) {
        float m = -INFINITY;
        for (int i = 0; i < 16; ++i) m = fmaxf(m, vals[i]);
        float sum = 0.0f;
        for (int i = 0; i < 16; ++i) sum += expf(vals[i] - m);
        out[c] = expf(vals[c] - m) / sum;
    }
}

extern "C" void kernel_launch(void* const* d_in, const int* in_sizes, int n_in,
                              void* d_out, int out_size, void* d_ws, size_t ws_size,
                              hipStream_t stream) {
    const float* x = (const float*)d_in[0];
    const int* edge = (const int*)d_in[1];
    const float* W1 = (const float*)d_in[2];
    const float* b1 = (const float*)d_in[3];
    const float* W2 = (const float*)d_in[4];
    const float* b2 = (const float*)d_in[5];
    const int* src = edge;
    const int* dst = edge + NE;

    char* ws = (char*)d_ws;
    int* bucket_cnt = (int*)ws;                   // NB
    int* bucket_start = bucket_cnt + NB;          // NB+1
    int* bcursor = bucket_start + NB + 1;         // NB
    unsigned* packed = (unsigned*)(bcursor + NB); // NE
    float* dinv = (float*)(packed + NE);          // NN
    float* hs = dinv + NN;                        // NN*16
    float* hs2 = hs + (size_t)NN * 16;            // NN*16
    float* pooled = hs2 + (size_t)NN * 16;        // 16

    float* out = (float*)d_out;

    k_init<<<1, 1024, 0, stream>>>(bucket_cnt, pooled);
    k_bcount<<<128, 256, 0, stream>>>(dst, bucket_cnt);
    k_prep<<<1, 1024, 0, stream>>>(bucket_cnt, bucket_start, bcursor);
    k_place<<<(NE + 255) / 256, 256, 0, stream>>>(src, dst, bcursor, packed);
    k_dinv<<<NB, 256, 0, stream>>>(packed, bucket_start, dinv);
    k_gemm1<<<(NTILE + 3) / 4, 256, 0, stream>>>(x, W1, dinv, hs);
    k_agg1<<<NB, 256, 0, stream>>>(hs, dinv, bucket_start, packed, W2, b1, hs2);
    k_agg2<<<NB, 256, 0, stream>>>(hs2, dinv, bucket_start, packed, pooled);
    k_softmax<<<1, 64, 0, stream>>>(pooled, b2, out);
}

// Round 5
// 557.091 us; speedup vs baseline: 3.1993x; 3.1993x over previous
//
#include <hip/hip_runtime.h>
#include <hip/hip_bf16.h>
#include <math.h>

#define NN 100000
#define NE 3200000
#define NF 512
#define NTILE 6250   // NN/16 exactly
#define NB 782       // ceil(NN/128) dst-buckets of 128 nodes
#define NCH 256      // edge chunks
#define CHUNK 12500  // NE/NCH exactly
#define HSZ (NB * NCH)  // 200192
#define NSB1 ((HSZ + 1023) / 1024)  // 196

typedef __attribute__((ext_vector_type(8))) short short8;
typedef __attribute__((ext_vector_type(4))) float f32x4;

__device__ inline unsigned bf16_rne(float f) {
    unsigned u = __builtin_bit_cast(unsigned, f);
    return (u + 0x7FFFu + ((u >> 16) & 1u)) >> 16;
}
__device__ inline float bf16_back(unsigned h) {
    return __builtin_bit_cast(float, h << 16);
}

// ---------------- pooled=0 ----------------
__global__ void k_initp(float* __restrict__ pooled) {
    if (threadIdx.x < 16) pooled[threadIdx.x] = 0.0f;
}

// ---------------- per-chunk bucket histogram (LDS, no global atomics) ---------
__global__ __launch_bounds__(256) void k_hist(const int* __restrict__ dst,
                                              int* __restrict__ hist) {
    __shared__ int lcnt[NB];
    for (int i = threadIdx.x; i < NB; i += 256) lcnt[i] = 0;
    __syncthreads();
    const int e0 = blockIdx.x * CHUNK;
    for (int i = threadIdx.x; i < CHUNK; i += 256)
        atomicAdd(&lcnt[dst[e0 + i] >> 7], 1);
    __syncthreads();
    for (int b = threadIdx.x; b < NB; b += 256)
        hist[b * NCH + blockIdx.x] = lcnt[b];
}

// ---------------- 3-kernel exclusive scan of hist (in place) ----------------
__global__ __launch_bounds__(1024) void k_scan1(int* __restrict__ hist,
                                                int* __restrict__ bsum) {
    __shared__ int tmp[2][1024];
    int tid = threadIdx.x;
    int i = blockIdx.x * 1024 + tid;
    int v = (i < HSZ) ? hist[i] : 0;
    int pp = 0;
    tmp[0][tid] = v;
    __syncthreads();
    for (int off = 1; off < 1024; off <<= 1) {
        int t = tmp[pp][tid];
        if (tid >= off) t += tmp[pp][tid - off];
        tmp[1 - pp][tid] = t;
        __syncthreads();
        pp = 1 - pp;
    }
    int incl = tmp[pp][tid];
    if (i < HSZ) hist[i] = incl - v;  // exclusive, sans block offset
    if (tid == 1023) bsum[blockIdx.x] = incl;
}

__global__ __launch_bounds__(256) void k_scan2(int* __restrict__ bsum) {
    __shared__ int tmp[2][256];
    int tid = threadIdx.x;
    int v = (tid < NSB1) ? bsum[tid] : 0;
    int pp = 0;
    tmp[0][tid] = v;
    __syncthreads();
    for (int off = 1; off < 256; off <<= 1) {
        int t = tmp[pp][tid];
        if (tid >= off) t += tmp[pp][tid - off];
        tmp[1 - pp][tid] = t;
        __syncthreads();
        pp = 1 - pp;
    }
    if (tid < NSB1) bsum[tid] = tmp[pp][tid] - v;  // exclusive
}

__global__ __launch_bounds__(256) void k_scan3(int* __restrict__ hist,
                                               const int* __restrict__ bsum) {
    int i = blockIdx.x * 256 + threadIdx.x;
    if (i < HSZ) hist[i] += bsum[i >> 10];
    if (i == 0) hist[HSZ] = NE;
}

// ---------------- placement: LDS cursors, zero global atomics ----------------
__global__ __launch_bounds__(256) void k_place2(const int* __restrict__ src,
                                                const int* __restrict__ dst,
                                                const int* __restrict__ hist,
                                                unsigned* __restrict__ packed) {
    __shared__ int sbase[NB];
    __shared__ int lcur[NB];
    const int c = blockIdx.x;
    for (int b = threadIdx.x; b < NB; b += 256) {
        sbase[b] = hist[b * NCH + c];
        lcur[b] = 0;
    }
    __syncthreads();
    const int e0 = c * CHUNK;
    for (int i = threadIdx.x; i < CHUNK; i += 256) {
        int d = dst[e0 + i];
        int s = src[e0 + i];
        int b = d >> 7;
        int pos = atomicAdd(&lcur[b], 1);
        packed[sbase[b] + pos] = ((unsigned)(d & 127) << 17) | (unsigned)s;
    }
}

// ---------------- per-bucket counting sort -> node CSR (+dinv), in place ------
#define BCAP 8192  // 64 sigma above mean bucket size 4093
__global__ __launch_bounds__(256) void k_bsort(unsigned* __restrict__ packed,
                                               const int* __restrict__ hist,
                                               int* __restrict__ row_start,
                                               float* __restrict__ dinv) {
    __shared__ unsigned stage[BCAP];
    __shared__ int cnt[128];
    __shared__ int t0[128], t1[128];
    const int tid = threadIdx.x;
    const int b = blockIdx.x;
    const int beg = hist[b * NCH], end = hist[(b + 1) * NCH];
    const int sz = end - beg;
    if (tid < 128) cnt[tid] = 0;
    __syncthreads();
    for (int i = tid; i < sz; i += 256) {
        unsigned p = packed[beg + i];
        if (i < BCAP) stage[i] = p;
        atomicAdd(&cnt[p >> 17], 1);
    }
    __syncthreads();
    // inclusive Hillis-Steele scan over 128 counts
    if (tid < 128) t0[tid] = cnt[tid];
    __syncthreads();
    int pp = 0;
    for (int off = 1; off < 128; off <<= 1) {
        if (tid < 128) {
            int t = (pp ? t1[tid] : t0[tid]);
            if (tid >= off) t += (pp ? t1[tid - off] : t0[tid - off]);
            if (pp) t0[tid] = t; else t1[tid] = t;
        }
        __syncthreads();
        pp = 1 - pp;
    }
    if (tid < 128) {
        int incl = pp ? t1[tid] : t0[tid];
        int excl = incl - cnt[tid];
        int n = b * 128 + tid;
        if (n < NN) {
            row_start[n] = beg + excl;
            dinv[n] = rsqrtf((float)cnt[tid] + 1.0f);
        }
        cnt[tid] = excl;  // reuse as cursor
    }
    __syncthreads();
    for (int i = tid; i < sz; i += 256) {
        unsigned p = (i < BCAP) ? stage[i] : packed[beg + i];
        int k = p >> 17;
        int pos = atomicAdd(&cnt[k], 1);
        packed[beg + pos] = p & 0x1FFFFu;
    }
    if (b == NB - 1 && tid == 0) row_start[NN] = NE;
}

// ---------------- GEMM1 via MFMA 16x16x32 bf16, split hi/lo ----------------
// Writes hs[n][c] = dinv[n] * (x@W1)[n][c]
__global__ __launch_bounds__(256) void k_gemm1(
    const float* __restrict__ x, const float* __restrict__ W1,
    const float* __restrict__ dinv, float* __restrict__ hs) {
    __shared__ short8 Bh[1024];  // idx = (kk*4+q)*16 + c
    __shared__ short8 Bl[1024];

    const int t = threadIdx.x;
    {   // stage W: thread (c,q,kk0) handles kk = kk0*4+i
        const int c = t & 15, q = (t >> 4) & 3, kk0 = t >> 6;
        for (int i = 0; i < 4; ++i) {
            const int kk = kk0 * 4 + i;
            short8 hi, lo;
#pragma unroll
            for (int j = 0; j < 8; ++j) {
                float w = W1[(kk * 32 + q * 8 + j) * 16 + c];
                unsigned h = bf16_rne(w);
                float back = bf16_back(h);
                unsigned l = bf16_rne(w - back);
                hi[j] = (short)h;
                lo[j] = (short)l;
            }
            Bh[(kk * 4 + q) * 16 + c] = hi;
            Bl[(kk * 4 + q) * 16 + c] = lo;
        }
    }
    __syncthreads();

    const int lane = t & 63;
    const int wave = blockIdx.x * 4 + (t >> 6);
    if (wave >= NTILE) return;
    const int nb = wave * 16;
    const int m = lane & 15;  // A row within tile AND B/C col (channel)
    const int q = lane >> 4;

    const float4* xrow = (const float4*)(x + (size_t)(nb + m) * NF + q * 8);
    float4 xr[32];
#pragma unroll
    for (int kk = 0; kk < 16; ++kk) {
        xr[2 * kk] = xrow[kk * 8];
        xr[2 * kk + 1] = xrow[kk * 8 + 1];
    }

    f32x4 acc = {0.f, 0.f, 0.f, 0.f};
#pragma unroll
    for (int kk = 0; kk < 16; ++kk) {
        float f[8] = {xr[2 * kk].x,     xr[2 * kk].y,     xr[2 * kk].z,
                      xr[2 * kk].w,     xr[2 * kk + 1].x, xr[2 * kk + 1].y,
                      xr[2 * kk + 1].z, xr[2 * kk + 1].w};
        short8 ah, al;
#pragma unroll
        for (int j = 0; j < 8; ++j) {
            unsigned h = bf16_rne(f[j]);
            ah[j] = (short)h;
            al[j] = (short)bf16_rne(f[j] - bf16_back(h));
        }
        short8 bh = Bh[(kk * 4 + q) * 16 + m];
        short8 bl = Bl[(kk * 4 + q) * 16 + m];
        acc = __builtin_amdgcn_mfma_f32_16x16x32_bf16(ah, bh, acc, 0, 0, 0);
        acc = __builtin_amdgcn_mfma_f32_16x16x32_bf16(ah, bl, acc, 0, 0, 0);
        acc = __builtin_amdgcn_mfma_f32_16x16x32_bf16(al, bh, acc, 0, 0, 0);
    }

    // C/D: col=lane&15, row=q*4+reg
#pragma unroll
    for (int r = 0; r < 4; ++r) {
        const int n = nb + q * 4 + r;
        hs[n * 16 + m] = dinv[n] * acc[r];
    }
}

// ---------------- gather: out[n] = dinv[n]*(hs[n] + sum_{s in N(n)} hs[s]) ------
// one wave per node; lanes = (edge subgroup g=lane>>4) x (channel c=lane&15)
__global__ __launch_bounds__(256) void k_gather(
    const float* __restrict__ hs, const float* __restrict__ dinv,
    const int* __restrict__ row_start, const int* __restrict__ csr,
    float* __restrict__ out) {
    const int lane = threadIdx.x & 63;
    const int n = blockIdx.x * 4 + (threadIdx.x >> 6);
    const int c = lane & 15;
    const int g = lane >> 4;
    const int beg = row_start[n], end = row_start[n + 1];
    float acc = 0.0f;
    int i = beg + g;
    for (; i + 4 < end; i += 8) {  // 2 edges per group per iter (MLP)
        int s0 = csr[i];
        int s1 = csr[i + 4];
        acc += hs[s0 * 16 + c];
        acc += hs[s1 * 16 + c];
    }
    if (i < end) {
        int s0 = csr[i];
        acc += hs[s0 * 16 + c];
    }
    acc += __shfl_xor(acc, 16, 64);
    acc += __shfl_xor(acc, 32, 64);
    if (lane < 16) out[n * 16 + c] = dinv[n] * (acc + hs[n * 16 + c]);
}

// ---------------- GEMM2: hs2[n] = dinv[n] * (relu(a1+b1) @ W2) ----------------
__global__ void k_gemm2(const float* __restrict__ a1, const float* __restrict__ W2,
                        const float* __restrict__ b1, const float* __restrict__ dinv,
                        float* __restrict__ hs2) {
    int n = blockIdx.x * blockDim.x + threadIdx.x;
    if (n >= NN) return;
    float hv[16];
    {
        const float4* row = (const float4*)(a1 + (size_t)n * 16);
        ((float4*)hv)[0] = row[0];
        ((float4*)hv)[1] = row[1];
        ((float4*)hv)[2] = row[2];
        ((float4*)hv)[3] = row[3];
    }
    float acc[16];
#pragma unroll
    for (int c = 0; c < 16; ++c) acc[c] = 0.0f;
#pragma unroll
    for (int c = 0; c < 16; ++c) {
        float hc = fmaxf(hv[c] + b1[c], 0.0f);
#pragma unroll
        for (int c2 = 0; c2 < 16; ++c2) acc[c2] += hc * W2[c * 16 + c2];
    }
    float di = dinv[n];
    float oo[16];
#pragma unroll
    for (int c = 0; c < 16; ++c) oo[c] = di * acc[c];
    float4* orow = (float4*)(hs2 + (size_t)n * 16);
    orow[0] = ((float4*)oo)[0];
    orow[1] = ((float4*)oo)[1];
    orow[2] = ((float4*)oo)[2];
    orow[3] = ((float4*)oo)[3];
}

// ---------------- reduce: pooled[c] = sum_n out2[n][c] ----------------
__global__ void k_reduce(const float* __restrict__ out2, float* __restrict__ pooled) {
    int t = blockIdx.x * blockDim.x + threadIdx.x;
    int c = t & 15;
    int n0 = t >> 4;
    int nstride = (gridDim.x * blockDim.x) >> 4;
    float s = 0.0f;
    for (int n = n0; n < NN; n += nstride) s += out2[n * 16 + c];
    s += __shfl_xor(s, 16, 64);
    s += __shfl_xor(s, 32, 64);
    __shared__ float red[4][16];
    int wid = threadIdx.x >> 6;
    int lane = threadIdx.x & 63;
    if (lane < 16) red[wid][lane] = s;
    __syncthreads();
    if (threadIdx.x < 16) {
        float tot = red[0][threadIdx.x] + red[1][threadIdx.x] + red[2][threadIdx.x] +
                    red[3][threadIdx.x];
        atomicAdd(&pooled[threadIdx.x], tot);
    }
}

// ---------------- softmax over 16 pooled means + b2 ----------------
__global__ void k_softmax(const float* __restrict__ pooled,
                          const float* __restrict__ b2, float* __restrict__ out) {
    __shared__ float vals[16];
    int c = threadIdx.x;
    if (c < 16) vals[c] = pooled[c] * (1.0f / NN) + b2[c];
    __syncthreads();
    if (c < 16) {
        float m = -INFINITY;
        for (int i = 0; i < 16; ++i) m = fmaxf(m, vals[i]);
        float sum = 0.0f;
        for (int i = 0; i < 16; ++i) sum += expf(vals[i] - m);
        out[c] = expf(vals[c] - m) / sum;
    }
}

extern "C" void kernel_launch(void* const* d_in, const int* in_sizes, int n_in,
                              void* d_out, int out_size, void* d_ws, size_t ws_size,
                              hipStream_t stream) {
    const float* x = (const float*)d_in[0];
    const int* edge = (const int*)d_in[1];
    const float* W1 = (const float*)d_in[2];
    const float* b1 = (const float*)d_in[3];
    const float* W2 = (const float*)d_in[4];
    const float* b2 = (const float*)d_in[5];
    const int* src = edge;
    const int* dst = edge + NE;

    char* ws = (char*)d_ws;
    int* hist = (int*)ws;                          // HSZ+1
    int* bsum = hist + HSZ + 1;                    // 256
    unsigned* packed = (unsigned*)(bsum + 256);    // NE (becomes csr)
    int* row_start = (int*)(packed + NE);          // NN+1
    float* dinv = (float*)(row_start + NN + 1);    // NN
    float* hs = dinv + NN;                         // NN*16
    float* abuf = hs + (size_t)NN * 16;            // NN*16
    float* pooled = abuf + (size_t)NN * 16;        // 16

    float* out = (float*)d_out;
    const int* csr = (const int*)packed;

    k_initp<<<1, 64, 0, stream>>>(pooled);
    k_hist<<<NCH, 256, 0, stream>>>(dst, hist);
    k_scan1<<<NSB1, 1024, 0, stream>>>(hist, bsum);
    k_scan2<<<1, 256, 0, stream>>>(bsum);
    k_scan3<<<(HSZ + 255) / 256, 256, 0, stream>>>(hist, bsum);
    k_place2<<<NCH, 256, 0, stream>>>(src, dst, hist, packed);
    k_bsort<<<NB, 256, 0, stream>>>(packed, hist, row_start, dinv);

    k_gemm1<<<(NTILE + 3) / 4, 256, 0, stream>>>(x, W1, dinv, hs);
    k_gather<<<NN / 4, 256, 0, stream>>>(hs, dinv, row_start, csr, abuf);
    k_gemm2<<<(NN + 255) / 256, 256, 0, stream>>>(abuf, W2, b1, dinv, hs);
    k_gather<<<NN / 4, 256, 0, stream>>>(hs, dinv, row_start, csr, abuf);
    k_reduce<<<256, 256, 0, stream>>>(abuf, pooled);
    k_softmax<<<1, 64, 0, stream>>>(pooled, b2, out);
}